// Round 8
// baseline (708.098 us; speedup 1.0000x reference)
//
#include <hip/hip_runtime.h>

#define CC 128
#define HH 128
#define WW 128
#define DH 64
#define DW 64
#define LTOT 4096          // DH*DW patches / fg positions
#define K0S 384            // 3*128 split-concat K for the pixel-pair GEMM
#define K2 2048            // CC*4*4
#define SCALE_F 10.0f
#define IMG ((size_t)CC * HH * WW)

typedef __attribute__((ext_vector_type(8))) short short8;
typedef __attribute__((ext_vector_type(4))) float f32x4;

// ---- pointer-pack structs (batch-merged dispatch via blockIdx.z) ----
struct Prep4 { const float* src[4]; unsigned short* dst[4]; int lo[4]; };
struct PtrS2 { const float* b[2]; float* ssq[2]; };
struct PtrN2 { const float* ssq[2]; float* invn[2]; float* mmv[2]; };
struct PtrR2 { const float* src[2]; unsigned short* dst[2]; };
struct PtrG  { const unsigned short* A[2]; const unsigned short* B[2]; float* C[2]; };
struct PtrO2 { const float* C2[2]; float* out[2]; };

// ---- bf16 helpers (RNE) ----
__device__ __forceinline__ unsigned short f2bf(float x) {
    union { float f; unsigned u; } v; v.f = x;
    unsigned r = v.u + 0x7fffu + ((v.u >> 16) & 1u);
    return (unsigned short)(r >> 16);
}
__device__ __forceinline__ float bf2f(unsigned short b) {
    union { unsigned u; float f; } v; v.u = ((unsigned)b) << 16;
    return v.f;
}

#define GLDS16(g, l) __builtin_amdgcn_global_load_lds( \
    (const __attribute__((address_space(1))) void*)(g), \
    (__attribute__((address_space(3))) void*)(l), 16, 0, 0)

// ---------------- downsample (::2) + fp32->bf16 split, row n = pixel, 384 = 3 segs * 128 ch ----
// b gets [hi, lo, hi], f gets [hi, hi, lo]  =>  products sum to hi*hi + lo*hi + hi*lo
__global__ __launch_bounds__(128) void split_ds_kernel(Prep4 P) {
    int z = blockIdx.z;
    const float* __restrict__ src = P.src[z];
    unsigned short* __restrict__ dst = P.dst[z];
    int lo_in_seg1 = P.lo[z];
    int n = blockIdx.x;          // 4096 pixels
    int c = threadIdx.x;         // 128 channels
    int ny = n >> 6, nx = n & 63;
    float v = src[((size_t)c * HH + 2 * ny) * WW + 2 * nx];
    unsigned short hi = f2bf(v);
    unsigned short lo = f2bf(v - bf2f(hi));
    unsigned short* drow = dst + (size_t)n * K0S;
    drow[c]       = hi;
    drow[128 + c] = lo_in_seg1 ? lo : hi;
    drow[256 + c] = lo_in_seg1 ? hi : lo;
}

// ---------------- raw 4x4 stride-2 patches of full-res b, transposed: dst[m2][p] bf16 ----------------
__global__ __launch_bounds__(256) void im2col_rawt_kernel(PtrR2 P) {
    int z = blockIdx.z;
    const float* __restrict__ src = P.src[z];
    unsigned short* __restrict__ dst = P.dst[z];
    int idx = blockIdx.x * 256 + threadIdx.x;   // K2*LTOT threads, p fastest
    int p = idx & (LTOT - 1);
    int m = idx >> 12;
    int px = p & 63, py = p >> 6;
    int ke = m & 3, kd = (m >> 2) & 3, c = m >> 4;
    int yy = 2 * py - 1 + kd, xx = 2 * px - 1 + ke;
    float v = 0.f;
    if (yy >= 0 && yy < HH && xx >= 0 && xx < WW)
        v = src[((size_t)c * HH + yy) * WW + xx];
    dst[idx] = f2bf(v);
}

// ---------------- per-pixel sum of squares over channels (on downsampled b) ----------------
__global__ void ssq_kernel(PtrS2 P) {
    int z = blockIdx.z;
    const float* __restrict__ b = P.b[z];
    float* __restrict__ ssq = P.ssq[z];
    int p = blockIdx.x * blockDim.x + threadIdx.x;     // 4096
    int px = p & 63, py = p >> 6;
    float s = 0.f;
    for (int c = 0; c < CC; ++c) {
        float v = b[((size_t)c * HH + 2 * py) * WW + 2 * px];
        s += v * v;
    }
    ssq[p] = s;
}

// ---------------- patch inverse norm + mask gate ----------------
__global__ void norm_mm_kernel(PtrN2 P, const float* __restrict__ mask) {
    int z = blockIdx.z;
    const float* __restrict__ ssq = P.ssq[z];
    float* __restrict__ inv_norm = P.invn[z];
    float* __restrict__ mmv = P.mmv[z];
    int p = blockIdx.x * blockDim.x + threadIdx.x;     // 4096
    int px = p & 63, py = p >> 6;
    float s = 0.f, ms = 0.f;
    for (int di = -1; di <= 1; ++di)
        for (int dj = -1; dj <= 1; ++dj) {
            int y = py + di, x = px + dj;
            if (y >= 0 && y < DH && x >= 0 && x < DW) {
                s += ssq[y * 64 + x];
                ms += mask[(size_t)(2 * y) * WW + 2 * x];
            }
        }
    float n = sqrtf(s);
    if (n < 1e-4f) n = 1e-4f;
    inv_norm[p] = 1.f / n;
    mmv[p] = (ms == 0.f) ? 1.f : 0.f;
}

// ---------------- bf16 MFMA GEMM (m97 structure + XOR bank swizzle), batch via blockIdx.z ----------------
// A[M][K], B[N][K], C[M][N] fp32. 128x128 tile, BK=32, 4 waves 2x2, 4x4 MFMA 16x16x32.
// LDS slot s (16B chunks) of row m holds global k-chunk s ^ ((m>>1)&3).
__global__ __launch_bounds__(256) void gemm_mfma(PtrG G, int M, int N, int K)
{
    __shared__ short As[128 * 32];   // [m][k-chunk swizzled] rows of 64B
    __shared__ short Bs[128 * 32];
    int z = blockIdx.z;
    const unsigned short* __restrict__ Aop = G.A[z];
    const unsigned short* __restrict__ Bop = G.B[z];
    float* __restrict__ C = G.C[z];
    int tid = threadIdx.x;
    int wave = tid >> 6, lane = tid & 63;
    int wm = (wave >> 1) * 64;
    int wn = (wave & 1) * 64;
    int bm = blockIdx.y * 128, bn = blockIdx.x * 128;

    int rowS = wave * 32;                 // this wave stages rows [rowS, rowS+32)
    int lrow = lane >> 2;                 // 0..15 within 16-row group
    int lcol = (((lane & 3) ^ ((lrow >> 1) & 3)) * 8);

    f32x4 acc[4][4] = {};

    int quad = lane >> 4;                 // k-slab for MFMA fragments
    int r16 = lane & 15;
    int slotA = (quad ^ ((r16 >> 1) & 3)) * 8;   // un-swizzle at read

    for (int k0 = 0; k0 < K; k0 += 32) {
        const unsigned short* ag = Aop + (size_t)(bm + rowS + lrow) * K + k0 + lcol;
        const unsigned short* bg = Bop + (size_t)(bn + rowS + lrow) * K + k0 + lcol;
        GLDS16(ag,                  As + rowS * 32);
        GLDS16(ag + 16 * (size_t)K, As + (rowS + 16) * 32);
        GLDS16(bg,                  Bs + rowS * 32);
        GLDS16(bg + 16 * (size_t)K, Bs + (rowS + 16) * 32);
        __syncthreads();

        short8 a[4], b[4];
#pragma unroll
        for (int i = 0; i < 4; ++i) {
            a[i] = *(const short8*)&As[(wm + i * 16 + r16) * 32 + slotA];
            b[i] = *(const short8*)&Bs[(wn + i * 16 + r16) * 32 + slotA];
        }
#pragma unroll
        for (int i = 0; i < 4; ++i)
#pragma unroll
            for (int j = 0; j < 4; ++j)
                acc[i][j] = __builtin_amdgcn_mfma_f32_16x16x32_bf16(a[i], b[j], acc[i][j], 0, 0, 0);
        __syncthreads();
    }

    int col = lane & 15, rq = (lane >> 4) * 4;
#pragma unroll
    for (int i = 0; i < 4; ++i) {
#pragma unroll
        for (int r = 0; r < 4; ++r) {
            int m = bm + wm + i * 16 + rq + r;
#pragma unroll
            for (int j = 0; j < 4; ++j)
                C[(size_t)m * N + bn + wn + j * 16 + col] = acc[i][j][r];
        }
    }
}

// ---------------- 9-tap patch stencil: S[q][p] = invn[p] * sum_{u,v} C[q+δ][p+δ], δ=64du+dv ----------------
// Tap (du,dv) valid iff qy+du,qx+dv,py+du,px+dv all in [0,64)  (2D zero-pad of both patches).
// XCD swizzle: blocks with equal (blk&7) share an XCD and own a contiguous 512-row q range.
__global__ __launch_bounds__(256) void stencil_norm_kernel(
    const float* __restrict__ C, const float* __restrict__ invn,
    float* __restrict__ Sout)
{
    int blk = blockIdx.x;
    int q = ((blk & 7) << 9) | (blk >> 3);
    int t = threadIdx.x;
    int qy = q >> 6, qx = q & 63;
    int px = t & 63;
    int py0 = t >> 6;
    float acc[16] = {};
#pragma unroll
    for (int du = -1; du <= 1; ++du) {
        if (qy + du < 0 || qy + du > 63) continue;
#pragma unroll
        for (int dv = -1; dv <= 1; ++dv) {
            if (qx + dv < 0 || qx + dv > 63) continue;
            if (px + dv < 0 || px + dv > 63) continue;
            const float* row = C + (size_t)(q + 64 * du + dv) * LTOT + 64 * du + dv;
#pragma unroll
            for (int i = 0; i < 16; ++i) {
                int py = py0 + 4 * i;
                if (py + du < 0 || py + du > 63) continue;
                acc[i] += row[t + 256 * i];
            }
        }
    }
    float* orow = Sout + (size_t)q * LTOT;
#pragma unroll
    for (int i = 0; i < 16; ++i)
        orow[t + 256 * i] = acc[i] * invn[t + 256 * i];
}

// ---------------- fused: (fuse2 o fuse1) 9-tap diagonal stencil + row softmax + bf16 write ----------------
__global__ __launch_bounds__(256) void fused_conv_softmax_kernel(
    const float* __restrict__ S, const float* __restrict__ mmv,
    unsigned short* __restrict__ S16)
{
    __shared__ float redmax[4];
    __shared__ float redsum[4];
    int blk = blockIdx.x;
    int q = ((blk & 7) << 9) | (blk >> 3);
    int t = threadIdx.x;
    int lane = t & 63, wid = t >> 6;

    int rbase = ((q & 63) << 6) | (q >> 6);     // swap(q)
    int rrs[3];
    bool rok[3];
#pragma unroll
    for (int j = 0; j < 3; ++j) {
        int r2 = rbase + (j - 1);
        rok[j] = (r2 >= 0) && (r2 < LTOT);
        rrs[j] = ((r2 & 63) << 6) | ((r2 >> 6) & 63);   // swap(r2)
    }

    float v[16], m[16];
#pragma unroll
    for (int i = 0; i < 16; ++i) {
        int c = t + (i << 8);                   // column p, 0..4095
        int cbase = ((c & 63) << 6) | (c >> 6); // swap(c)
        float s = 0.f;
#pragma unroll
        for (int j = 0; j < 3; ++j) {           // d2 = j-1 (fuse2 order)
            if (!rok[j]) continue;
            int c2 = cbase + (j - 1);
            if (c2 < 0 || c2 >= LTOT) continue;
            int cc = ((c2 & 63) << 6) | (c2 >> 6);  // swap(c2); interior: c + 64*d2
            int rr = rrs[j];
            float tsum = 0.f;
#pragma unroll
            for (int d1 = -1; d1 <= 1; ++d1) {  // fuse1 order
                int a = rr + d1, bcol = cc + d1;
                if (a >= 0 && a < LTOT && bcol >= 0 && bcol < LTOT)
                    tsum += S[(size_t)a * LTOT + bcol];
            }
            s += tsum;
        }
        float mmx = mmv[c];
        m[i] = mmx;
        v[i] = s * mmx * SCALE_F;
    }

    float mx = v[0];
#pragma unroll
    for (int i = 1; i < 16; ++i) mx = fmaxf(mx, v[i]);
#pragma unroll
    for (int o = 32; o; o >>= 1) mx = fmaxf(mx, __shfl_xor(mx, o));
    if (lane == 0) redmax[wid] = mx;
    __syncthreads();
    float gmx = fmaxf(fmaxf(redmax[0], redmax[1]), fmaxf(redmax[2], redmax[3]));

    float s = 0.f;
#pragma unroll
    for (int i = 0; i < 16; ++i) {
        v[i] = __expf(v[i] - gmx);
        s += v[i];
    }
#pragma unroll
    for (int o = 32; o; o >>= 1) s += __shfl_xor(s, o);
    if (lane == 0) redsum[wid] = s;
    __syncthreads();
    float inv = 1.f / (redsum[0] + redsum[1] + redsum[2] + redsum[3]);

    unsigned short* orow = S16 + (size_t)q * LTOT;
#pragma unroll
    for (int i = 0; i < 16; ++i)
        orow[t + (i << 8)] = f2bf(v[i] * inv * m[i]);
}

// ---------------- overlap-add of weighted 4x4 patches (stride 2), /4 ----------------
__global__ void output_kernel(PtrO2 P) {
    int z = blockIdx.z;
    const float* __restrict__ C2 = P.C2[z];
    float* __restrict__ out = P.out[z];
    int idx = blockIdx.x * blockDim.x + threadIdx.x;   // CC*HH*WW
    int x = idx & 127;
    int y = (idx >> 7) & 127;
    int c = idx >> 14;
    int oylo = max(0, (y - 1) >> 1), oyhi = min(63, (y + 1) >> 1);
    int oxlo = max(0, (x - 1) >> 1), oxhi = min(63, (x + 1) >> 1);
    float s = 0.f;
    for (int oy = oylo; oy <= oyhi; ++oy)
        for (int ox = oxlo; ox <= oxhi; ++ox) {
            int kd = y - 2 * oy + 1;
            int ke = x - 2 * ox + 1;
            s += C2[(size_t)(oy * 64 + ox) * K2 + c * 16 + kd * 4 + ke];
        }
    out[idx] = s * 0.25f;
}

extern "C" void kernel_launch(void* const* d_in, const int* in_sizes, int n_in,
                              void* d_out, int out_size, void* d_ws, size_t ws_size,
                              hipStream_t stream) {
    (void)in_sizes; (void)n_in; (void)out_size;
    const float* f    = (const float*)d_in[0];
    const float* b    = (const float*)d_in[1];
    const float* mask = (const float*)d_in[2];
    float* out = (float*)d_out;

    const size_t SZ_MAT  = (size_t)LTOT * LTOT * 4;   // 64 MB
    const size_t SZ_HALF = SZ_MAT / 2;                // 32 MB
    const size_t SZ_WR   = (size_t)K2 * LTOT * 2;     // 16 MB
    const size_t SZ_SP   = (size_t)LTOT * K0S * 2;    // 3 MB
    const size_t SZ_V    = (size_t)LTOT * 4;

    auto pad = [](size_t n) { return (n + 255) & ~(size_t)255; };
    const size_t need_merged = pad(SZ_MAT) * 3 + pad(SZ_HALF) + pad(SZ_WR) * 2
                             + pad(SZ_SP) * 4 + pad(SZ_V) * 6 + 4096;

    char* p = (char*)d_ws;
    auto take = [&](size_t n) -> void* { void* r = (void*)p; p += pad(n); return r; };

    const float* f0 = f,  *b0 = b;
    const float* f1 = f + IMG, *b1 = b + IMG;

    if (ws_size >= need_merged) {
        // ---------- batch-merged path (~270 MB workspace) ----------
        float* A  = (float*)take(SZ_MAT);   // Cpix (b0 then b1); S16_1 = first 32MB after fused(b1)
        float* Bb = (float*)take(SZ_MAT);   // Sp0 -> C2_0
        float* Cc = (float*)take(SZ_MAT);   // Sp1 -> C2_1
        unsigned short* D  = (unsigned short*)take(SZ_HALF);   // S16_0
        unsigned short* W0 = (unsigned short*)take(SZ_WR);
        unsigned short* W1 = (unsigned short*)take(SZ_WR);
        unsigned short* Bsp0 = (unsigned short*)take(SZ_SP);
        unsigned short* Fsp0 = (unsigned short*)take(SZ_SP);
        unsigned short* Bsp1 = (unsigned short*)take(SZ_SP);
        unsigned short* Fsp1 = (unsigned short*)take(SZ_SP);
        float* ssq0 = (float*)take(SZ_V); float* ssq1 = (float*)take(SZ_V);
        float* invn0 = (float*)take(SZ_V); float* invn1 = (float*)take(SZ_V);
        float* mmv0 = (float*)take(SZ_V); float* mmv1 = (float*)take(SZ_V);

        Prep4 P{{b0, f0, b1, f1}, {Bsp0, Fsp0, Bsp1, Fsp1}, {1, 0, 1, 0}};
        split_ds_kernel<<<dim3(LTOT, 1, 4), 128, 0, stream>>>(P);
        PtrS2 sq{{b0, b1}, {ssq0, ssq1}};
        ssq_kernel<<<dim3(16, 1, 2), 256, 0, stream>>>(sq);
        PtrN2 nm{{ssq0, ssq1}, {invn0, invn1}, {mmv0, mmv1}};
        norm_mm_kernel<<<dim3(16, 1, 2), 256, 0, stream>>>(nm, mask);
        PtrR2 rw{{b0, b1}, {W0, W1}};
        im2col_rawt_kernel<<<dim3((size_t)K2 * LTOT / 256, 1, 2), 256, 0, stream>>>(rw);

        // batch 0: Cpix -> Sp0 -> S16_0
        PtrG g10{{Fsp0, nullptr}, {Bsp0, nullptr}, {A, nullptr}};
        gemm_mfma<<<dim3(32, 32, 1), 256, 0, stream>>>(g10, LTOT, LTOT, K0S);
        stencil_norm_kernel<<<LTOT, 256, 0, stream>>>(A, invn0, Bb);
        fused_conv_softmax_kernel<<<LTOT, 256, 0, stream>>>(Bb, mmv0, D);

        // batch 1: Cpix -> Sp1 -> S16_1 (into A; Cpix dead after stencil)
        PtrG g11{{Fsp1, nullptr}, {Bsp1, nullptr}, {A, nullptr}};
        gemm_mfma<<<dim3(32, 32, 1), 256, 0, stream>>>(g11, LTOT, LTOT, K0S);
        stencil_norm_kernel<<<LTOT, 256, 0, stream>>>(A, invn1, Cc);
        fused_conv_softmax_kernel<<<LTOT, 256, 0, stream>>>(Cc, mmv1, (unsigned short*)A);

        // merged GEMM2 (1024 blocks): C2_bi[q][m2] = sum_p S16_bi[q][p] * W_bi[m2][p]
        PtrG g2{{D, (unsigned short*)A}, {W0, W1}, {Bb, Cc}};
        gemm_mfma<<<dim3(K2 / 128, LTOT / 128, 2), 256, 0, stream>>>(g2, LTOT, K2, LTOT);

        PtrO2 o2{{Bb, Cc}, {out, out + IMG}};
        output_kernel<<<dim3(CC * HH * WW / 256, 1, 2), 256, 0, stream>>>(o2);
    } else {
        // ---------- fallback: exact R7 sequential path (~155 MB) ----------
        float* A  = (float*)take(SZ_MAT);   // Cpix -> S16
        float* Bb = (float*)take(SZ_MAT);   // Sp -> C2
        unsigned short* W   = (unsigned short*)take(SZ_WR);
        unsigned short* Bsp = (unsigned short*)take(SZ_SP);
        unsigned short* Fsp = (unsigned short*)take(SZ_SP);
        float* ssq  = (float*)take(SZ_V);
        float* invn = (float*)take(SZ_V);
        float* mmv  = (float*)take(SZ_V);

        for (int bi = 0; bi < 2; ++bi) {
            const float* fb = (bi == 0) ? f0 : f1;
            const float* bb = (bi == 0) ? b0 : b1;

            Prep4 P{{bb, fb, nullptr, nullptr}, {Bsp, Fsp, nullptr, nullptr}, {1, 0, 0, 0}};
            split_ds_kernel<<<dim3(LTOT, 1, 2), 128, 0, stream>>>(P);
            PtrS2 sq{{bb, nullptr}, {ssq, nullptr}};
            ssq_kernel<<<dim3(16, 1, 1), 256, 0, stream>>>(sq);
            PtrN2 nm{{ssq, nullptr}, {invn, nullptr}, {mmv, nullptr}};
            norm_mm_kernel<<<dim3(16, 1, 1), 256, 0, stream>>>(nm, mask);

            PtrG g1{{Fsp, nullptr}, {Bsp, nullptr}, {A, nullptr}};
            gemm_mfma<<<dim3(32, 32, 1), 256, 0, stream>>>(g1, LTOT, LTOT, K0S);
            stencil_norm_kernel<<<LTOT, 256, 0, stream>>>(A, invn, Bb);

            PtrR2 rw{{bb, nullptr}, {W, nullptr}};
            im2col_rawt_kernel<<<dim3((size_t)K2 * LTOT / 256, 1, 1), 256, 0, stream>>>(rw);

            fused_conv_softmax_kernel<<<LTOT, 256, 0, stream>>>(Bb, mmv, (unsigned short*)A);

            PtrG g2{{(unsigned short*)A, nullptr}, {W, nullptr}, {Bb, nullptr}};
            gemm_mfma<<<dim3(K2 / 128, LTOT / 128, 1), 256, 0, stream>>>(g2, LTOT, K2, LTOT);

            PtrO2 o2{{Bb, nullptr}, {out + (size_t)bi * IMG, nullptr}};
            output_kernel<<<dim3(CC * HH * WW / 256, 1, 1), 256, 0, stream>>>(o2);
        }
    }
}